// Round 14
// baseline (273.758 us; speedup 1.0000x reference)
//
#include <hip/hip_runtime.h>

typedef _Float16 f16;
typedef f16 f16x2 __attribute__((ext_vector_type(2)));
typedef f16 f16x8 __attribute__((ext_vector_type(8)));
typedef __fp16 h2v __attribute__((ext_vector_type(2)));
typedef float f32x4 __attribute__((ext_vector_type(4)));
typedef float f32x16 __attribute__((ext_vector_type(16)));
typedef unsigned int uint;

#define NCH 16
#define NB 32
#define NH 256
#define NW 256
#define HW 65536
#define CHW 1048576

// weight image (f16 A-frags + f32 bias frags): f16x8 idx WF1=0, WF2=1024, WF3=3072, WF4=5120
#define BIAS_BYTE 90112
#define WS_BYTES 91648
// x tile: f32 [ch16][rr10][cc66], staged by global_load_lds DMA
#define XT_OFF 91648
#define XT_FLOATS (16*10*66)
#define LDS_TOTAL (WS_BYTES + XT_FLOATS*4)   // 133888

__global__ void prep_k(const float* __restrict__ w1, const float* __restrict__ w2,
                       const float* __restrict__ w3, const float* __restrict__ w4,
                       const float* __restrict__ b1, const float* __restrict__ b2,
                       const float* __restrict__ b3, float* __restrict__ wsf) {
  f16* wf = (f16*)wsf;
  int id = blockIdx.x * 256 + threadIdx.x;
  if (id < 8192) {
    int j = id & 7, l = (id >> 3) & 63, mt = (id >> 9) & 3, kt = id >> 11;
    int o = mt * 32 + (l & 31), c = kt * 16 + (l >> 5) * 8 + j;
    wf[id] = (f16)w1[o * 64 + c];
  } else if (id < 24576) {
    int t = id - 8192;
    int j = t & 7, l = (t >> 3) & 63, mt = (t >> 9) & 3, kt = t >> 11;
    int o = mt * 32 + (l & 31), c = kt * 16 + (l >> 5) * 8 + j;
    wf[8192 + t] = (f16)w2[o * 128 + c];
  } else if (id < 40960) {
    int t = id - 24576;
    int j = t & 7, l = (t >> 3) & 63, mt = (t >> 9) & 3, kt = t >> 11;
    int o = mt * 32 + (l & 31), c = kt * 16 + (l >> 5) * 8 + j;
    wf[24576 + t] = (f16)w3[o * 128 + c];
  } else if (id < 45056) {
    int t = id - 40960;
    int j = t & 7, l = (t >> 3) & 63, kt = t >> 9;
    int m = l & 31, hh = l >> 5;
    int c = kt * 16 + hh * 8 + j;
    wf[40960 + t] = (m < 16) ? (f16)w4[m * 128 + c] : (f16)0.f;
  } else if (id < 45440) {
    int t = id - 45056;
    int r = t & 15, hh = (t >> 4) & 1, mt = (t >> 5) & 3, ly = t >> 7;
    const float* bb = (ly == 0) ? b1 : (ly == 1) ? b2 : b3;
    ((float*)((unsigned char*)wsf + BIAS_BYTE))[t] =
        bb[mt * 32 + (r & 3) + 8 * (r >> 2) + 4 * hh];
  }
}

__device__ __forceinline__ void pl32swap(uint& a, uint& b) {
  asm volatile("v_permlane32_swap_b32 %0, %1" : "+v"(a), "+v"(b));
}

__device__ __forceinline__ f16x8 mk8(uint a, uint b, uint c, uint d) {
  union { uint u[4]; f16x8 v; } z;
  z.u[0] = a; z.u[1] = b; z.u[2] = c; z.u[3] = d;
  return z.v;
}

__device__ __forceinline__ void gload_lds4(const float* g, float* l) {
  __builtin_amdgcn_global_load_lds(
      (const __attribute__((address_space(1))) unsigned int*)(const void*)g,
      (__attribute__((address_space(3))) unsigned int*)(void*)l, 4, 0, 0);
}

// Single-half layer: bias init from LDS frags + MFMA cluster.
// Per-wave state: acc 64 AGPR + one B array 32 VGPR -> fits 128-reg/wave budget
// so 16 waves/block (4 waves/SIMD) are resident.
template <int NKT>
__device__ __forceinline__ void gemm_half(const unsigned char* __restrict__ smem,
                                          int wfFragBase, int biasFloatOff, int lane, int hi,
                                          const f16x8* __restrict__ B, f32x16 acc[4]) {
#pragma unroll
  for (int mt = 0; mt < 4; ++mt) {
    const f32x16* bp =
        (const f32x16*)(smem + BIAS_BYTE + 4 * (biasFloatOff + (mt * 2 + hi) * 16));
    acc[mt] = *bp;
  }
  const f16x8* A = (const f16x8*)smem + wfFragBase + lane;
  __builtin_amdgcn_s_setprio(1);
#pragma unroll
  for (int kt = 0; kt < NKT; ++kt) {
#pragma unroll
    for (int mt = 0; mt < 4; ++mt) {
      f16x8 a = A[(kt * 4 + mt) * 64];
      acc[mt] = __builtin_amdgcn_mfma_f32_32x32x16_f16(a, B[kt], acc[mt], 0, 0, 0);
    }
  }
  __builtin_amdgcn_s_setprio(0);
}

// lrelu in packed f16 (cvt_pkrtz + pk_mul + pk_max) -> permlane -> next B-frags
__device__ __forceinline__ void epilogue_swap(const f32x16 acc[4], f16x8 Bn[8]) {
  uint w[32];
  const h2v c001 = {(__fp16)0.01f, (__fp16)0.01f};
#pragma unroll
  for (int mt = 0; mt < 4; ++mt) {
#pragma unroll
    for (int i = 0; i < 8; ++i) {
      h2v u = __builtin_amdgcn_cvt_pkrtz(acc[mt][2 * i], acc[mt][2 * i + 1]);
      h2v s = u * c001;
      h2v m = __builtin_elementwise_max(u, s);
      w[mt * 8 + i] = __builtin_bit_cast(uint, m);
    }
  }
#pragma unroll
  for (int kt = 0; kt < 8; ++kt) {
    int mt = kt >> 1, sub = kt & 1;
    int W = mt * 8 + sub * 4;
    uint a0 = w[W], a1 = w[W + 1], a2 = w[W + 2], a3 = w[W + 3];
    pl32swap(a0, a2);
    pl32swap(a1, a3);
    Bn[kt] = mk8(a0, a1, a2, a3);
  }
}

// perception for one 32-px half from f32 tile: stencil math -> L1 B-frags
__device__ __forceinline__ void perception_f32(const float* __restrict__ xt,
                                               int row8, int pc, int hi, int h, f16x8 B1h[4]) {
  const int px = h * 32 + pc;
  uint yw[16];
#pragma unroll
  for (int kt = 0; kt < 4; ++kt) {
#pragma unroll
    for (int cp = 0; cp < 2; ++cp) {
      int c = kt * 4 + hi * 2 + cp;
      const float* xr = &xt[(c * 10 + row8) * 66 + px];
      float v00 = xr[0],   v01 = xr[1],   v02 = xr[2];
      float v10 = xr[66],  v11 = xr[67],  v12 = xr[68];
      float v20 = xr[132], v21 = xr[133], v22 = xr[134];
      float rs0 = v00 + v01 + v02, rs2 = v20 + v21 + v22;
      float fsx = (v02 - v00) + (v22 - v20) + 2.f * (v12 - v10);
      float fsy = (rs2 - rs0) + (v21 - v01);
      float flap = (rs0 + rs2 + v10 + v12) - 8.f * v11;
      h2v t0 = __builtin_amdgcn_cvt_pkrtz(v11, fsx);
      h2v t1 = __builtin_amdgcn_cvt_pkrtz(fsy, flap);
      yw[kt * 4 + cp * 2 + 0] = __builtin_bit_cast(uint, t0);
      yw[kt * 4 + cp * 2 + 1] = __builtin_bit_cast(uint, t1);
    }
  }
#pragma unroll
  for (int kt = 0; kt < 4; ++kt)
    B1h[kt] = mk8(yw[kt * 4], yw[kt * 4 + 1], yw[kt * 4 + 2], yw[kt * 4 + 3]);
}

// DMA one tile's interior: wave wv (0..15) covers channel wv, 10 rows; div-free
__device__ __forceinline__ void issue_tile_dma(const float* __restrict__ xb,
                                               float* __restrict__ xt,
                                               int cx, int ry, int ch, int lane) {
  const int gc0 = cx * 64;
#pragma unroll
  for (int rr = 0; rr < 10; ++rr) {
    int gr = ry * 8 + rr - 1;
    float* ldst = xt + (ch * 10 + rr) * 66 + 1;
    if ((unsigned)gr < (unsigned)NH) {
      const float* g = xb + ((size_t)ch << 16) + (gr << 8) + gc0 + lane;
      gload_lds4(g, ldst);
    } else {
      ldst[lane] = 0.f;
    }
  }
}

// edge-column fixup: load early (reg), store late
__device__ __forceinline__ float fixup_load(const float* __restrict__ xb,
                                            int cx, int ry, int tid) {
  if (tid >= 320) return 0.f;
  int row = tid >> 1, side = tid & 1;
  int ch = row / 10;
  int rr = row - ch * 10;
  int gr = ry * 8 + rr - 1;
  int gc = cx * 64 - 1 + side * 65;
  float v = 0.f;
  if ((unsigned)gr < (unsigned)NH && (unsigned)gc < (unsigned)NW)
    v = xb[((size_t)ch << 16) + (gr << 8) + gc];
  return v;
}

__device__ __forceinline__ void fixup_store(float* __restrict__ xt, int tid, float v) {
  if (tid < 320) {
    int row = tid >> 1, side = tid & 1;
    xt[row * 66 + side * 65] = v;
  }
}

__global__ __launch_bounds__(1024, 1)
void nca_mlp_k(const float* __restrict__ x, const float* __restrict__ wsf,
               const float* __restrict__ mask, float* __restrict__ xn) {
  extern __shared__ unsigned char smem[];
  float* xt = (float*)(smem + XT_OFF);
  const int tid = threadIdx.x;
  const int lane = tid & 63;
  const int wv = tid >> 6;      // 0..15
  const int row8 = wv >> 1;     // tile row 0..7
  const int h = wv & 1;         // column half
  const int pc = lane & 31;
  const int hi = lane >> 5;

  const int tile0 = blockIdx.x * 16;
  const int b = tile0 >> 7;                 // constant per block
  const float* xb = x + (size_t)b * CHW;
  float* xnb = xn + (size_t)b * CHW;
  const float* mb = mask + (size_t)b * HW;

  // ---- stage weights+bias once (linear b128 copy) ----
  {
    const uint4* src = (const uint4*)wsf;
    uint4* dst = (uint4*)smem;
    for (int i = tid; i < WS_BYTES / 16; i += 1024) dst[i] = src[i];
  }
  // ---- prefetch first tile ----
  {
    int cx = tile0 & 3, ry = (tile0 >> 2) & 31;
    issue_tile_dma(xb, xt, cx, ry, wv, lane);
    float fv = fixup_load(xb, cx, ry, tid);
    fixup_store(xt, tid, fv);
  }
  __syncthreads();              // drains vmcnt (DMA) + lgkm (weights, fixup)

  for (int t = 0; t < 16; ++t) {
    const int tile = tile0 + t;
    const int cx = tile & 3, ry = (tile >> 2) & 31;

    // ---- perception (consumer of xt) ----
    f16x8 B1[4];
    perception_f32(xt, row8, pc, hi, h, B1);

    // ---- update-x values: read exact f32 from xt (interior) before xt is reused ----
    float xv[8];
#pragma unroll
    for (int r = 0; r < 8; ++r) {
      int ch = (r & 3) + 8 * (r >> 2) + 4 * hi;
      xv[r] = xt[(ch * 10 + row8 + 1) * 66 + h * 32 + pc + 1];
    }
    __syncthreads();            // everyone done reading xt

    // ---- issue next tile's DMA; drains at the iteration-end barrier ----
    float fv = 0.f;
    if (t < 15) {
      int cx2 = (tile + 1) & 3, ry2 = ((tile + 1) >> 2) & 31;
      issue_tile_dma(xb, xt, cx2, ry2, wv, lane);
      fv = fixup_load(xb, cx2, ry2, tid);
    }

    // ---- MLP chain (single half) ----
    f32x16 acc[4];
    f16x8 B2[8], B3[8], B4[8];

    gemm_half<4>(smem, 0, 0, lane, hi, B1, acc);
    epilogue_swap(acc, B2);
    gemm_half<8>(smem, 1024, 128, lane, hi, B2, acc);
    epilogue_swap(acc, B3);
    gemm_half<8>(smem, 3072, 256, lane, hi, B3, acc);
    epilogue_swap(acc, B4);

    f32x16 a4;
#pragma unroll
    for (int r = 0; r < 16; ++r) a4[r] = 0.f;
    {
      const f16x8* A4 = (const f16x8*)smem + 5120 + lane;
      __builtin_amdgcn_s_setprio(1);
#pragma unroll
      for (int kt = 0; kt < 8; ++kt)
        a4 = __builtin_amdgcn_mfma_f32_32x32x16_f16(A4[kt * 64], B4[kt], a4, 0, 0, 0);
      __builtin_amdgcn_s_setprio(0);
    }

    // ---- update: x_new = x(LDS) + dy * mask ----
    {
      const int row = ry * 8 + row8;
      const int col = cx * 64 + h * 32 + pc;
      float* xob = xnb + (row << 8) + col;
      const float mv = mb[(row << 8) + col];
#pragma unroll
      for (int r = 0; r < 8; ++r) {
        int ch = (r & 3) + 8 * (r >> 2) + 4 * hi;
        xob[(size_t)ch << 16] = xv[r] + a4[r] * mv;
      }
    }

    if (t < 15) fixup_store(xt, tid, fv);
    __syncthreads();            // drains DMA vmcnt + lgkm -> xt(t+1) ready
  }
}

// alive factor: row-block with LDS horizontal-max sharing; zero dead pixels
__global__ void alive_scale_k(const float* __restrict__ x, float* __restrict__ xn) {
  __shared__ float pm[4][258];
  const int col = threadIdx.x;
  const int row = blockIdx.x;
  const int b = blockIdx.y;
  const float NEG = -3.0e38f;
  float v0 = NEG, v1 = NEG, v2 = NEG, v3 = NEG;
  const size_t base0 = (size_t)b * CHW + ((size_t)row << 8) + col;
#pragma unroll
  for (int dr = -1; dr <= 1; ++dr) {
    int rr = row + dr;
    if ((unsigned)rr < NH) {
      long o = (long)base0 + dr * NW;
      v0 = fmaxf(v0, x[o]);
      v1 = fmaxf(v1, x[o + HW]);
      v2 = fmaxf(v2, xn[o]);
      v3 = fmaxf(v3, xn[o + HW]);
    }
  }
  pm[0][col + 1] = v0;
  pm[1][col + 1] = v1;
  pm[2][col + 1] = v2;
  pm[3][col + 1] = v3;
  if (col == 0) {
#pragma unroll
    for (int f = 0; f < 4; ++f) { pm[f][0] = NEG; pm[f][257] = NEG; }
  }
  __syncthreads();
  float p0 = fmaxf(fmaxf(pm[0][col], pm[0][col + 1]), pm[0][col + 2]);
  float p1 = fmaxf(fmaxf(pm[1][col], pm[1][col + 1]), pm[1][col + 2]);
  float p2 = fmaxf(fmaxf(pm[2][col], pm[2][col + 1]), pm[2][col + 2]);
  float p3 = fmaxf(fmaxf(pm[3][col], pm[3][col + 1]), pm[3][col + 2]);
  bool alive = ((fabsf(p0) + fabsf(p1)) > 0.01f) && ((fabsf(p2) + fabsf(p3)) > 0.01f);
  if (!alive) {
#pragma unroll
    for (int ch = 0; ch < NCH; ++ch) xn[base0 + ((size_t)ch << 16)] = 0.f;
  }
}

extern "C" void kernel_launch(void* const* d_in, const int* in_sizes, int n_in,
                              void* d_out, int out_size, void* d_ws, size_t ws_size,
                              hipStream_t stream) {
  const float* x    = (const float*)d_in[0];
  const float* w1   = (const float*)d_in[1];
  const float* b1   = (const float*)d_in[2];
  const float* w2   = (const float*)d_in[3];
  const float* b2   = (const float*)d_in[4];
  const float* w3   = (const float*)d_in[5];
  const float* b3   = (const float*)d_in[6];
  const float* w4   = (const float*)d_in[7];
  const float* mask = (const float*)d_in[8];

  float* wsf = (float*)d_ws;
  float* xn = (float*)d_out;

  hipFuncSetAttribute(reinterpret_cast<const void*>(nca_mlp_k),
                      hipFuncAttributeMaxDynamicSharedMemorySize, LDS_TOTAL);

  prep_k<<<178, 256, 0, stream>>>(w1, w2, w3, w4, b1, b2, b3, wsf);
  nca_mlp_k<<<256, 1024, LDS_TOTAL, stream>>>(x, wsf, mask, xn);
  alive_scale_k<<<dim3(NH, NB), 256, 0, stream>>>(x, xn);
}

// Round 15
// 251.430 us; speedup vs baseline: 1.0888x; 1.0888x over previous
//
#include <hip/hip_runtime.h>

typedef _Float16 f16;
typedef f16 f16x2 __attribute__((ext_vector_type(2)));
typedef f16 f16x8 __attribute__((ext_vector_type(8)));
typedef __fp16 h2v __attribute__((ext_vector_type(2)));
typedef float f32x4 __attribute__((ext_vector_type(4)));
typedef float f32x16 __attribute__((ext_vector_type(16)));
typedef unsigned int uint;

#define NCH 16
#define NB 32
#define NH 256
#define NW 256
#define HW 65536
#define CHW 1048576

// weight image (f16 A-frags + f32 bias frags): f16x8 idx WF1=0, WF2=1024, WF3=3072, WF4=5120
#define BIAS_BYTE 90112
#define WS_BYTES 91648
// x tile: f32 [ch16][rr10][cc66], staged by global_load_lds DMA
#define XT_OFF 91648
#define XT_FLOATS (16*10*66)
#define LDS_TOTAL (WS_BYTES + XT_FLOATS*4)   // 133888

__global__ void prep_k(const float* __restrict__ w1, const float* __restrict__ w2,
                       const float* __restrict__ w3, const float* __restrict__ w4,
                       const float* __restrict__ b1, const float* __restrict__ b2,
                       const float* __restrict__ b3, float* __restrict__ wsf) {
  f16* wf = (f16*)wsf;
  int id = blockIdx.x * 256 + threadIdx.x;
  if (id < 8192) {
    int j = id & 7, l = (id >> 3) & 63, mt = (id >> 9) & 3, kt = id >> 11;
    int o = mt * 32 + (l & 31), c = kt * 16 + (l >> 5) * 8 + j;
    wf[id] = (f16)w1[o * 64 + c];
  } else if (id < 24576) {
    int t = id - 8192;
    int j = t & 7, l = (t >> 3) & 63, mt = (t >> 9) & 3, kt = t >> 11;
    int o = mt * 32 + (l & 31), c = kt * 16 + (l >> 5) * 8 + j;
    wf[8192 + t] = (f16)w2[o * 128 + c];
  } else if (id < 40960) {
    int t = id - 24576;
    int j = t & 7, l = (t >> 3) & 63, mt = (t >> 9) & 3, kt = t >> 11;
    int o = mt * 32 + (l & 31), c = kt * 16 + (l >> 5) * 8 + j;
    wf[24576 + t] = (f16)w3[o * 128 + c];
  } else if (id < 45056) {
    int t = id - 40960;
    int j = t & 7, l = (t >> 3) & 63, kt = t >> 9;
    int m = l & 31, hh = l >> 5;
    int c = kt * 16 + hh * 8 + j;
    wf[40960 + t] = (m < 16) ? (f16)w4[m * 128 + c] : (f16)0.f;
  } else if (id < 45440) {
    int t = id - 45056;
    int r = t & 15, hh = (t >> 4) & 1, mt = (t >> 5) & 3, ly = t >> 7;
    const float* bb = (ly == 0) ? b1 : (ly == 1) ? b2 : b3;
    ((float*)((unsigned char*)wsf + BIAS_BYTE))[t] =
        bb[mt * 32 + (r & 3) + 8 * (r >> 2) + 4 * hh];
  }
}

__device__ __forceinline__ void pl32swap(uint& a, uint& b) {
  asm volatile("v_permlane32_swap_b32 %0, %1" : "+v"(a), "+v"(b));
}

__device__ __forceinline__ f16x8 mk8(uint a, uint b, uint c, uint d) {
  union { uint u[4]; f16x8 v; } z;
  z.u[0] = a; z.u[1] = b; z.u[2] = c; z.u[3] = d;
  return z.v;
}

__device__ __forceinline__ void gload_lds4(const float* g, float* l) {
  __builtin_amdgcn_global_load_lds(
      (const __attribute__((address_space(1))) unsigned int*)(const void*)g,
      (__attribute__((address_space(3))) unsigned int*)(void*)l, 4, 0, 0);
}

// barrier #1: xt readers done. Their ds_read results are already consumed
// (data deps force lgkm waits), so only lgkmcnt(0)+s_barrier is needed —
// avoids the vmcnt(0) store/DMA drain __syncthreads would emit.
__device__ __forceinline__ void barrier_lds_only() {
  asm volatile("s_waitcnt lgkmcnt(0)" ::: "memory");
  __builtin_amdgcn_s_barrier();
  __builtin_amdgcn_sched_barrier(0);
}

// barrier #2: DMA loads must be landed; the 8 output stores are the NEWEST
// vmem ops (all loads issued before any store), so vmcnt(8) proves all loads
// retired while letting stores stay in flight across the barrier.
__device__ __forceinline__ void barrier_dma_ready() {
  asm volatile("s_waitcnt vmcnt(8) lgkmcnt(0)" ::: "memory");
  __builtin_amdgcn_s_barrier();
  __builtin_amdgcn_sched_barrier(0);
}

// Single-half layer: bias init from LDS frags + MFMA cluster.
template <int NKT>
__device__ __forceinline__ void gemm_half(const unsigned char* __restrict__ smem,
                                          int wfFragBase, int biasFloatOff, int lane, int hi,
                                          const f16x8* __restrict__ B, f32x16 acc[4]) {
#pragma unroll
  for (int mt = 0; mt < 4; ++mt) {
    const f32x16* bp =
        (const f32x16*)(smem + BIAS_BYTE + 4 * (biasFloatOff + (mt * 2 + hi) * 16));
    acc[mt] = *bp;
  }
  const f16x8* A = (const f16x8*)smem + wfFragBase + lane;
  __builtin_amdgcn_s_setprio(1);
#pragma unroll
  for (int kt = 0; kt < NKT; ++kt) {
#pragma unroll
    for (int mt = 0; mt < 4; ++mt) {
      f16x8 a = A[(kt * 4 + mt) * 64];
      acc[mt] = __builtin_amdgcn_mfma_f32_32x32x16_f16(a, B[kt], acc[mt], 0, 0, 0);
    }
  }
  __builtin_amdgcn_s_setprio(0);
}

// lrelu in packed f16 (cvt_pkrtz + pk_mul + pk_max) -> permlane -> next B-frags
__device__ __forceinline__ void epilogue_swap(const f32x16 acc[4], f16x8 Bn[8]) {
  uint w[32];
  const h2v c001 = {(__fp16)0.01f, (__fp16)0.01f};
#pragma unroll
  for (int mt = 0; mt < 4; ++mt) {
#pragma unroll
    for (int i = 0; i < 8; ++i) {
      h2v u = __builtin_amdgcn_cvt_pkrtz(acc[mt][2 * i], acc[mt][2 * i + 1]);
      h2v s = u * c001;
      h2v m = __builtin_elementwise_max(u, s);
      w[mt * 8 + i] = __builtin_bit_cast(uint, m);
    }
  }
#pragma unroll
  for (int kt = 0; kt < 8; ++kt) {
    int mt = kt >> 1, sub = kt & 1;
    int W = mt * 8 + sub * 4;
    uint a0 = w[W], a1 = w[W + 1], a2 = w[W + 2], a3 = w[W + 3];
    pl32swap(a0, a2);
    pl32swap(a1, a3);
    Bn[kt] = mk8(a0, a1, a2, a3);
  }
}

// perception for one 32-px half from f32 tile: stencil math -> L1 B-frags
__device__ __forceinline__ void perception_f32(const float* __restrict__ xt,
                                               int row8, int pc, int hi, int h, f16x8 B1h[4]) {
  const int px = h * 32 + pc;
  uint yw[16];
#pragma unroll
  for (int kt = 0; kt < 4; ++kt) {
#pragma unroll
    for (int cp = 0; cp < 2; ++cp) {
      int c = kt * 4 + hi * 2 + cp;
      const float* xr = &xt[(c * 10 + row8) * 66 + px];
      float v00 = xr[0],   v01 = xr[1],   v02 = xr[2];
      float v10 = xr[66],  v11 = xr[67],  v12 = xr[68];
      float v20 = xr[132], v21 = xr[133], v22 = xr[134];
      float rs0 = v00 + v01 + v02, rs2 = v20 + v21 + v22;
      float fsx = (v02 - v00) + (v22 - v20) + 2.f * (v12 - v10);
      float fsy = (rs2 - rs0) + (v21 - v01);
      float flap = (rs0 + rs2 + v10 + v12) - 8.f * v11;
      h2v t0 = __builtin_amdgcn_cvt_pkrtz(v11, fsx);
      h2v t1 = __builtin_amdgcn_cvt_pkrtz(fsy, flap);
      yw[kt * 4 + cp * 2 + 0] = __builtin_bit_cast(uint, t0);
      yw[kt * 4 + cp * 2 + 1] = __builtin_bit_cast(uint, t1);
    }
  }
#pragma unroll
  for (int kt = 0; kt < 4; ++kt)
    B1h[kt] = mk8(yw[kt * 4], yw[kt * 4 + 1], yw[kt * 4 + 2], yw[kt * 4 + 3]);
}

// DMA one tile's interior: wave wv (0..15) covers channel wv, 10 rows; div-free
__device__ __forceinline__ void issue_tile_dma(const float* __restrict__ xb,
                                               float* __restrict__ xt,
                                               int cx, int ry, int ch, int lane) {
  const int gc0 = cx * 64;
#pragma unroll
  for (int rr = 0; rr < 10; ++rr) {
    int gr = ry * 8 + rr - 1;
    float* ldst = xt + (ch * 10 + rr) * 66 + 1;
    if ((unsigned)gr < (unsigned)NH) {
      const float* g = xb + ((size_t)ch << 16) + (gr << 8) + gc0 + lane;
      gload_lds4(g, ldst);
    } else {
      ldst[lane] = 0.f;
    }
  }
}

// edge-column fixup: load early (reg), store late
__device__ __forceinline__ float fixup_load(const float* __restrict__ xb,
                                            int cx, int ry, int tid) {
  if (tid >= 320) return 0.f;
  int row = tid >> 1, side = tid & 1;
  int ch = row / 10;
  int rr = row - ch * 10;
  int gr = ry * 8 + rr - 1;
  int gc = cx * 64 - 1 + side * 65;
  float v = 0.f;
  if ((unsigned)gr < (unsigned)NH && (unsigned)gc < (unsigned)NW)
    v = xb[((size_t)ch << 16) + (gr << 8) + gc];
  return v;
}

__device__ __forceinline__ void fixup_store(float* __restrict__ xt, int tid, float v) {
  if (tid < 320) {
    int row = tid >> 1, side = tid & 1;
    xt[row * 66 + side * 65] = v;
  }
}

__global__ __launch_bounds__(1024, 1)
void nca_mlp_k(const float* __restrict__ x, const float* __restrict__ wsf,
               const float* __restrict__ mask, float* __restrict__ xn) {
  extern __shared__ unsigned char smem[];
  float* xt = (float*)(smem + XT_OFF);
  const int tid = threadIdx.x;
  const int lane = tid & 63;
  const int wv = tid >> 6;      // 0..15
  const int row8 = wv >> 1;     // tile row 0..7
  const int h = wv & 1;         // column half
  const int pc = lane & 31;
  const int hi = lane >> 5;

  const int tile0 = blockIdx.x * 16;
  const int b = tile0 >> 7;                 // constant per block
  const float* xb = x + (size_t)b * CHW;
  float* xnb = xn + (size_t)b * CHW;
  const float* mb = mask + (size_t)b * HW;

  // ---- stage weights+bias once (linear b128 copy) ----
  {
    const uint4* src = (const uint4*)wsf;
    uint4* dst = (uint4*)smem;
    for (int i = tid; i < WS_BYTES / 16; i += 1024) dst[i] = src[i];
  }
  // ---- prefetch first tile ----
  {
    int cx = tile0 & 3, ry = (tile0 >> 2) & 31;
    issue_tile_dma(xb, xt, cx, ry, wv, lane);
    float fv = fixup_load(xb, cx, ry, tid);
    fixup_store(xt, tid, fv);
  }
  __syncthreads();              // full drain once at prologue

  for (int t = 0; t < 16; ++t) {
    const int tile = tile0 + t;
    const int cx = tile & 3, ry = (tile >> 2) & 31;

    // ---- perception (sole consumer of xt) ----
    f16x8 B1[4];
    perception_f32(xt, row8, pc, hi, h, B1);
    barrier_lds_only();         // readers done; no vmem drain

    // ---- issue next tile's DMA; lands by barrier #2 ----
    float fv = 0.f;
    if (t < 15) {
      int cx2 = (tile + 1) & 3, ry2 = ((tile + 1) >> 2) & 31;
      issue_tile_dma(xb, xt, cx2, ry2, wv, lane);
      fv = fixup_load(xb, cx2, ry2, tid);
    }

    // ---- MLP chain (single half) ----
    f32x16 acc[4];
    f16x8 B2[8], B3[8], B4[8];

    gemm_half<4>(smem, 0, 0, lane, hi, B1, acc);
    epilogue_swap(acc, B2);
    gemm_half<8>(smem, 1024, 128, lane, hi, B2, acc);
    epilogue_swap(acc, B3);
    gemm_half<8>(smem, 3072, 256, lane, hi, B3, acc);
    epilogue_swap(acc, B4);

    f32x16 a4;
#pragma unroll
    for (int r = 0; r < 16; ++r) a4[r] = 0.f;
    {
      const f16x8* A4 = (const f16x8*)smem + 5120 + lane;
      __builtin_amdgcn_s_setprio(1);
#pragma unroll
      for (int kt = 0; kt < 8; ++kt)
        a4 = __builtin_amdgcn_mfma_f32_32x32x16_f16(A4[kt * 64], B4[kt], a4, 0, 0, 0);
      __builtin_amdgcn_s_setprio(0);
    }

    // ---- update: x_new = x + dy * mask (x re-read from global, L2-hot;
    //      these loads are issued BEFORE the 8 stores -> vmcnt(8) proof holds)
    {
      const int row = ry * 8 + row8;
      const int col = cx * 64 + h * 32 + pc;
      const float* xrb = xb + (row << 8) + col;
      float* xob = xnb + (row << 8) + col;
      const float mv = mb[(row << 8) + col];
#pragma unroll
      for (int r = 0; r < 8; ++r) {
        int ch = (r & 3) + 8 * (r >> 2) + 4 * hi;
        xob[(size_t)ch << 16] = xrb[(size_t)ch << 16] + a4[r] * mv;
      }
    }

    if (t < 15) fixup_store(xt, tid, fv);
    barrier_dma_ready();        // DMA landed; stores may still be in flight
  }
}

// alive factor: row-block with LDS horizontal-max sharing; zero dead pixels
__global__ void alive_scale_k(const float* __restrict__ x, float* __restrict__ xn) {
  __shared__ float pm[4][258];
  const int col = threadIdx.x;
  const int row = blockIdx.x;
  const int b = blockIdx.y;
  const float NEG = -3.0e38f;
  float v0 = NEG, v1 = NEG, v2 = NEG, v3 = NEG;
  const size_t base0 = (size_t)b * CHW + ((size_t)row << 8) + col;
#pragma unroll
  for (int dr = -1; dr <= 1; ++dr) {
    int rr = row + dr;
    if ((unsigned)rr < NH) {
      long o = (long)base0 + dr * NW;
      v0 = fmaxf(v0, x[o]);
      v1 = fmaxf(v1, x[o + HW]);
      v2 = fmaxf(v2, xn[o]);
      v3 = fmaxf(v3, xn[o + HW]);
    }
  }
  pm[0][col + 1] = v0;
  pm[1][col + 1] = v1;
  pm[2][col + 1] = v2;
  pm[3][col + 1] = v3;
  if (col == 0) {
#pragma unroll
    for (int f = 0; f < 4; ++f) { pm[f][0] = NEG; pm[f][257] = NEG; }
  }
  __syncthreads();
  float p0 = fmaxf(fmaxf(pm[0][col], pm[0][col + 1]), pm[0][col + 2]);
  float p1 = fmaxf(fmaxf(pm[1][col], pm[1][col + 1]), pm[1][col + 2]);
  float p2 = fmaxf(fmaxf(pm[2][col], pm[2][col + 1]), pm[2][col + 2]);
  float p3 = fmaxf(fmaxf(pm[3][col], pm[3][col + 1]), pm[3][col + 2]);
  bool alive = ((fabsf(p0) + fabsf(p1)) > 0.01f) && ((fabsf(p2) + fabsf(p3)) > 0.01f);
  if (!alive) {
#pragma unroll
    for (int ch = 0; ch < NCH; ++ch) xn[base0 + ((size_t)ch << 16)] = 0.f;
  }
}

extern "C" void kernel_launch(void* const* d_in, const int* in_sizes, int n_in,
                              void* d_out, int out_size, void* d_ws, size_t ws_size,
                              hipStream_t stream) {
  const float* x    = (const float*)d_in[0];
  const float* w1   = (const float*)d_in[1];
  const float* b1   = (const float*)d_in[2];
  const float* w2   = (const float*)d_in[3];
  const float* b2   = (const float*)d_in[4];
  const float* w3   = (const float*)d_in[5];
  const float* b3   = (const float*)d_in[6];
  const float* w4   = (const float*)d_in[7];
  const float* mask = (const float*)d_in[8];

  float* wsf = (float*)d_ws;
  float* xn = (float*)d_out;

  hipFuncSetAttribute(reinterpret_cast<const void*>(nca_mlp_k),
                      hipFuncAttributeMaxDynamicSharedMemorySize, LDS_TOTAL);

  prep_k<<<178, 256, 0, stream>>>(w1, w2, w3, w4, b1, b2, b3, wsf);
  nca_mlp_k<<<256, 1024, LDS_TOTAL, stream>>>(x, wsf, mask, xn);
  alive_scale_k<<<dim3(NH, NB), 256, 0, stream>>>(x, xn);
}